// Round 1
// baseline (130.580 us; speedup 1.0000x reference)
//
#include <hip/hip_runtime.h>

// Fused UpFIRDn2d via banded MFMA chain: crop(1) -> +bias -> repeat-up x2 ->
// sep 12-tap FIR -> leaky_relu(0.2)*sqrt(2) -> sep 12-tap FIR -> down x2.
// x: (8,64,130,130) f32; out: (8,64,128,128) f32.
//
// Round 6: banded-K windows (each 16-wide output tile of an up-conv reads a
// 14-wide input window -> K=32, one MFMA; down-conv tiles read 42 -> K=64).
// 68 MFMA/block (was 122). 320 threads = 5 waves; tile counts 15/25/10
// divide evenly. Pads are computed zeros (constants zero outside band) -> no
// zero-fill phase.
// Round 7: LDS bank de-conflict. Old pitches 48/48/88/80 gave row bank-bases
// with period 4 (24*l15 mod 32 = {0,24,16,8}) -> 2-way conflict on every
// ds_read_b128 fragment read in S1/S2/S4 and 4-way on the S3 b16 scatter
// (160*q4 mod 32 = 0). New pitches: word-stride == +-4 or 12 (mod 32) so 8
// consecutive rows span 8 distinct 4-bank clusters, keeping 16B alignment:
//   XPITCH/BPITCH 48 -> 56 (28 words == -4 mod 32, period 8)
//   TPITCH       80 -> 88 (44 words == 12 mod 32, period 8; q4 term 16q4 -> 2-way)
//   UPITCH stays 88 (already period 8).
// LDS 26.4 KB -> 28.4 KB: 5 blocks/CU (25 waves) instead of 6 (30); measured
// avg occupancy was ~17 waves, so the slot loss should be non-binding.
// Stage algebra (verified round 5):
//   S1: B1[r][qq]  = sum_c  X[r][c]   * Gt[c][qq]    M48 N80 Kwin32
//   S2: U [pp][qq] = sum_r  G2[pp][r] * B1[r][qq]    M80 N80 Kwin32, then leaky
//   S3: T [a][qq]  = sum_pp D[a][pp]  * U[pp][qq]    M32 N80 Kwin64
//   S4: Out[a][j]  = sum_qq T[a][qq]  * D2t[qq][j]   M32 N32 Kwin64
// Edge clipping folded into 3 variants of D (by) and D2t (bx).

#define GAIN_C 1.4142135623730951f
#define NEG_C ((0.2f - 1.0f) * GAIN_C)

typedef short v8s __attribute__((ext_vector_type(8)));
typedef float v4f __attribute__((ext_vector_type(4)));

__device__ __forceinline__ int f2bf(float f) {   // fp32 -> bf16 bits (RNE)
    unsigned u = __float_as_uint(f);
    return (int)((u + 0x7FFFu + ((u >> 16) & 1u)) >> 16) & 0xFFFF;
}
__device__ __forceinline__ int pack_bf2(float a, float b) {
#if __has_builtin(__builtin_amdgcn_cvt_pk_bf16_f32)
    typedef __bf16 bf2 __attribute__((ext_vector_type(2)));
    bf2 r = __builtin_amdgcn_cvt_pk_bf16_f32(a, b);
    int o; __builtin_memcpy(&o, &r, 4); return o;
#else
    return f2bf(a) | (f2bf(b) << 16);
#endif
}

// band(x, q): up-conv weight linking local x index x to local up index q.
__device__ float band(int x, int q, const float* fu) {
    if (q >= 74 || x >= 43 || x < 0) return 0.f;
    int p = q >> 1, d = x - p;
    if (q & 1) {
        if (d < 0 || d > 6) return 0.f;
        if (d == 0) return fu[0];
        if (d == 6) return fu[11];
        return fu[2 * d - 1] + fu[2 * d];
    } else {
        if (d < 0 || d > 5) return 0.f;
        return fu[2 * d] + fu[2 * d + 1];
    }
}
// dband(o, q, v): down-conv weight, out index o, up index q; variant v:
// 0 = first tile (zero q<5), 2 = last tile (zero q>=69).
__device__ float dband(int o, int q, int v, const float* fd) {
    if (q >= 74 || q < 0) return 0.f;
    if (v == 0 && q < 5) return 0.f;
    if (v == 2 && q >= 69) return 0.f;
    int k = q - 2 * o;
    if (k < 0 || k > 11) return 0.f;
    return fd[k];
}

// ws layout (bf16): GtB 5x512 @0 | G2A 5x512 @2560 |
// DA 3var x (2mt x 2kt) x512 @5120 | D2B 3var x (2nt x 2kt) x512 @11264.
// Total 17408 shorts. K-window starts: S1/S2 k0 = min(8*t,16);
// S3/S4 k0 = t ? 16 : 0.  (Keep in sync with consumer kernel!)
__global__ __launch_bounds__(256) void build_consts(
    const float* __restrict__ fu, const float* __restrict__ fd,
    short* __restrict__ ws)
{
    int idx = blockIdx.x * 256 + threadIdx.x;   // grid covers 17408 exactly
    int l = (idx >> 3) & 63, j = idx & 7;
    int l15 = l & 15, kq = (l >> 4) * 8 + j;
    float val;
    if (idx < 2560) {                         // GtB: B-op, frag = nt
        int nt = idx >> 9;
        int k0 = 8 * nt < 16 ? 8 * nt : 16;
        val = band(k0 + kq, 16 * nt + l15, fu);
    } else if (idx < 5120) {                  // G2A: A-op, frag = mt
        int mt = (idx - 2560) >> 9;
        int k0 = 8 * mt < 16 ? 8 * mt : 16;
        val = band(k0 + kq, 16 * mt + l15, fu);
    } else if (idx < 11264) {                 // DA: A-op, frag = (v, mt*2+kt)
        int rel = idx - 5120;
        int v = rel >> 11, fi = (rel & 2047) >> 9;
        int mt = fi >> 1, kt = fi & 1;
        int pp = (mt ? 16 : 0) + 32 * kt + kq;
        val = dband(16 * mt + l15, pp, v, fd);
    } else {                                  // D2B: B-op, frag = (v, nt*2+kt)
        int rel = idx - 11264;
        int v = rel >> 11, fi = (rel & 2047) >> 9;
        int nt = fi >> 1, kt = fi & 1;
        int qq = (nt ? 16 : 0) + 32 * kt + kq;
        val = dband(16 * nt + l15, qq, v, fd);
    }
    ws[idx] = (short)f2bf(val);
}

#define XPITCH 56   // X [48 rows][56] bf16; 28 words == -4 mod 32 -> period-8 banks
#define BPITCH 56   // B1t [80 qq][56 r]
#define UPITCH 88   // Ut [80 qq][88 pp]; 44 words == 12 mod 32 (period 8, free)
#define TPITCH 88   // T [32 a][88 qq], aliases X/B1t-head region

__global__ __launch_bounds__(320, 8) void upfirdn_mfma(
    const float* __restrict__ xin_all,
    const float* __restrict__ bias,
    const short* __restrict__ cws,
    float* __restrict__ out)
{
    __shared__ __align__(16) short SH[2688 + 4480 + 7040];  // 28416 B
    short* Xl  = SH;            // 48x56  (dead after S1; T aliases)
    short* B1t = SH + 2688;     // 80x56  [qq][r] (dead after S2)
    short* Ut  = SH + 7168;     // 80x88  [qq][pp]
    short* T   = SH;            // 32x88  [a][qq] (overlaps Xl + head of B1t)

    const int tid  = threadIdx.x;
    const int lane = tid & 63, w = tid >> 6;
    const int l15  = lane & 15, q4 = lane >> 4;
    const int bx = blockIdx.x, by = blockIdx.y, bc = blockIdx.z;
    const int i0 = by * 32, j0 = bx * 32;

    const short* GtB = cws;
    const short* G2A = cws + 2560;
    const short* DA  = cws + 5120  + ((by == 0) ? 0 : (by == 3) ? 2 : 1) * 2048;
    const short* D2B = cws + 11264 + ((bx == 0) ? 0 : (bx == 3) ? 2 : 1) * 2048;

    // ---- Phase 0: load X tile (crop +1, +bias), pads zero. 48x24 int items
    // ---- written at int-pitch 28 (= XPITCH/2). Pad ints 24..27 never read. ----
    {
        const float* xp = xin_all + (size_t)bc * (130 * 130);
        const float bv = bias[bc & 63];
        const bool colInt = (bx == 1) | (bx == 2);
        int* Xli = (int*)Xl;
        for (int idx = tid; idx < 1152; idx += 320) {
            int r = idx / 24, cp = idx - r * 24;
            int gr = i0 - 5 + r;
            float f0 = 0.f, f1 = 0.f;
            if (r < 43 && (unsigned)gr < 128u && cp < 22) {
                const float* rowp = xp + (gr + 1) * 130 + 1;
                int gc0 = j0 - 5 + 2 * cp;
                if (colInt) {
                    f0 = rowp[gc0] + bv;
                    if (cp < 21) f1 = rowp[gc0 + 1] + bv;
                } else {
                    if ((unsigned)gc0 < 128u) f0 = rowp[gc0] + bv;
                    if (cp < 21 && (unsigned)(gc0 + 1) < 128u)
                        f1 = rowp[gc0 + 1] + bv;
                }
            }
            Xli[r * 28 + cp] = pack_bf2(f0, f1);
        }
    }
    __syncthreads();

    // ---- S1: B1 = X * Gt.  wave w -> nt = w; mt 0..2. K-window min(8nt,16). ----
    {
        const int nt = w;
        const int k0 = 8 * nt < 16 ? 8 * nt : 16;
        v8s bf = *(const v8s*)&GtB[nt * 512 + lane * 8];
#pragma unroll
        for (int mt = 0; mt < 3; ++mt) {
            v8s a = *(const v8s*)&Xl[(16 * mt + l15) * XPITCH + k0 + q4 * 8];
            v4f acc = {0.f, 0.f, 0.f, 0.f};
            acc = __builtin_amdgcn_mfma_f32_16x16x32_bf16(a, bf, acc, 0, 0, 0);
            // C: col = qq = 16nt+l15, rows r = 16mt + q4*4 + i
            *(int2*)&B1t[(16 * nt + l15) * BPITCH + 16 * mt + q4 * 4] =
                make_int2(pack_bf2(acc[0], acc[1]), pack_bf2(acc[2], acc[3]));
        }
    }
    __syncthreads();

    // ---- S2: U = leaky(G2 * B1).  wave w -> mt = w; nt 0..4. One A-frag/wave. ----
    {
        const int mt = w;
        const int k0 = 8 * mt < 16 ? 8 * mt : 16;
        v8s af = *(const v8s*)&G2A[mt * 512 + lane * 8];
#pragma unroll
        for (int nt = 0; nt < 5; ++nt) {
            v8s b = *(const v8s*)&B1t[(16 * nt + l15) * BPITCH + k0 + q4 * 8];
            v4f acc = {0.f, 0.f, 0.f, 0.f};
            acc = __builtin_amdgcn_mfma_f32_16x16x32_bf16(af, b, acc, 0, 0, 0);
#pragma unroll
            for (int i = 0; i < 4; ++i)
                acc[i] = GAIN_C * acc[i] + NEG_C * fminf(acc[i], 0.f);
            // C: col = qq = 16nt+l15, rows pp = 16mt + q4*4 + i
            *(int2*)&Ut[(16 * nt + l15) * UPITCH + 16 * mt + q4 * 4] =
                make_int2(pack_bf2(acc[0], acc[1]), pack_bf2(acc[2], acc[3]));
        }
    }
    __syncthreads();

    // ---- S3: T = D * U.  wave w -> nt = w; mt 0..1, K-window 64 @ (mt?16:0). ----
    {
        const int nt = w;
#pragma unroll
        for (int mt = 0; mt < 2; ++mt) {
            const int k0 = mt ? 16 : 0;
            v4f acc = {0.f, 0.f, 0.f, 0.f};
#pragma unroll
            for (int kt = 0; kt < 2; ++kt) {
                v8s a = *(const v8s*)&DA[(mt * 2 + kt) * 512 + lane * 8];
                v8s b = *(const v8s*)&Ut[(16 * nt + l15) * UPITCH
                                         + k0 + 32 * kt + q4 * 8];
                acc = __builtin_amdgcn_mfma_f32_16x16x32_bf16(a, b, acc, 0, 0, 0);
            }
            // C: col = qq = 16nt+l15, rows a = 16mt + q4*4 + i  (b16 scatter)
#pragma unroll
            for (int i = 0; i < 4; ++i)
                T[(16 * mt + q4 * 4 + i) * TPITCH + 16 * nt + l15] =
                    (short)f2bf(acc[i]);
        }
    }
    __syncthreads();

    // ---- S4: Out = T * D2t.  waves 0..3: (mt = w>>1, nt = w&1). ----
    if (w < 4) {
        const int mt = w >> 1, nt = w & 1;
        const int k0 = nt ? 16 : 0;
        v4f acc = {0.f, 0.f, 0.f, 0.f};
#pragma unroll
        for (int kt = 0; kt < 2; ++kt) {
            v8s a = *(const v8s*)&T[(16 * mt + l15) * TPITCH + k0 + 32 * kt + q4 * 8];
            v8s b = *(const v8s*)&D2B[(nt * 2 + kt) * 512 + lane * 8];
            acc = __builtin_amdgcn_mfma_f32_16x16x32_bf16(a, b, acc, 0, 0, 0);
        }
        float* op = out + (size_t)bc * 16384
                  + (size_t)(i0 + 16 * mt + q4 * 4) * 128 + (j0 + 16 * nt + l15);
#pragma unroll
        for (int i = 0; i < 4; ++i) op[i * 128] = acc[i];
    }
}

extern "C" void kernel_launch(void* const* d_in, const int* in_sizes, int n_in,
                              void* d_out, int out_size, void* d_ws, size_t ws_size,
                              hipStream_t stream) {
    const float* x  = (const float*)d_in[0];
    const float* bs = (const float*)d_in[1];
    const float* fu = (const float*)d_in[2];
    const float* fd = (const float*)d_in[3];
    float* outp = (float*)d_out;
    short* ws = (short*)d_ws;

    build_consts<<<68, 256, 0, stream>>>(fu, fd, ws);    // 17408 elems
    upfirdn_mfma<<<dim3(4, 4, 512), 320, 0, stream>>>(x, bs, ws, outp);
}

// Round 2
// 120.586 us; speedup vs baseline: 1.0829x; 1.0829x over previous
//
#include <hip/hip_runtime.h>

// Fused UpFIRDn2d via banded MFMA chain: crop(1) -> +bias -> repeat-up x2 ->
// sep 12-tap FIR -> leaky_relu(0.2)*sqrt(2) -> sep 12-tap FIR -> down x2.
// x: (8,64,130,130) f32; out: (8,64,128,128) f32.
//
// Round 8: 64x32 output tile (was 32x32), 8 waves (512 thr), grid (4,2,512)
// = 4096 blocks. Halves barriers per output, fills S4 with all waves,
// 126 MFMA/block vs 2x68. LDS 38.4 KB -> 4 blocks/CU x 8 waves = 32 waves
// (full cap, was 30). Round-6 bank-neutral pitches kept (24/44/76 words);
// round-7 taught pitch tuning is a dead end (conflicts ~11% tax, not the
// bottleneck).
// Stage algebra (row-dim now 64 out rows -> up-rows 138, x-rows 75):
//   S1: B1[r][qq]  = sum_c  X[r][c]   * Gt[c][qq]    M80  N80  Kwin32
//   S2: U [pp][qq] = sum_r  G2[pp][r] * B1[r][qq]    M144 N80  Kwin32, leaky
//   S3: T [a][qq]  = sum_pp D[a][pp]  * U[pp][qq]    M64  N80  Kwin64
//   S4: Out[a][j]  = sum_qq T[a][qq]  * D2t[qq][j]   M64  N32  Kwin64
// Edge clipping folded into 2 variants of D (by in {0,1}) and 3 of D2t (bx).

#define GAIN_C 1.4142135623730951f
#define NEG_C ((0.2f - 1.0f) * GAIN_C)

typedef short v8s __attribute__((ext_vector_type(8)));
typedef float v4f __attribute__((ext_vector_type(4)));

__device__ __forceinline__ int f2bf(float f) {   // fp32 -> bf16 bits (RNE)
    unsigned u = __float_as_uint(f);
    return (int)((u + 0x7FFFu + ((u >> 16) & 1u)) >> 16) & 0xFFFF;
}
__device__ __forceinline__ int pack_bf2(float a, float b) {
#if __has_builtin(__builtin_amdgcn_cvt_pk_bf16_f32)
    typedef __bf16 bf2 __attribute__((ext_vector_type(2)));
    bf2 r = __builtin_amdgcn_cvt_pk_bf16_f32(a, b);
    int o; __builtin_memcpy(&o, &r, 4); return o;
#else
    return f2bf(a) | (f2bf(b) << 16);
#endif
}

// band(x, q): up-conv weight linking local input index x to local up index q.
// qlim/xlim: valid extents of the local windows (cols: 74/43, rows: 138/75).
__device__ float band(int x, int q, int qlim, int xlim, const float* fu) {
    if (q >= qlim || x >= xlim || x < 0) return 0.f;
    int p = q >> 1, d = x - p;
    if (q & 1) {
        if (d < 0 || d > 6) return 0.f;
        if (d == 0) return fu[0];
        if (d == 6) return fu[11];
        return fu[2 * d - 1] + fu[2 * d];
    } else {
        if (d < 0 || d > 5) return 0.f;
        return fu[2 * d] + fu[2 * d + 1];
    }
}
// dband(o, q, v): down-conv weight, out index o, up index q; variant v:
// 0 = first tile (zero q<5), 2 = last tile (zero q>=qlim-5). qlim = up extent.
__device__ float dband(int o, int q, int v, int qlim, const float* fd) {
    if (q >= qlim || q < 0) return 0.f;
    if (v == 0 && q < 5) return 0.f;
    if (v == 2 && q >= qlim - 5) return 0.f;
    int k = q - 2 * o;
    if (k < 0 || k > 11) return 0.f;
    return fd[k];
}

// ws layout (bf16):
//   GtB 5nt x512            @0       (cols up: qlim 74, xlim 43, k0=min(8nt,16))
//   G2A 9mt x512            @2560    (rows up: qlim 138, xlim 75, k0=min(8mt,48))
//   DA  2v x (4mt x 2kt)x512 @7168   (rows dn: qlim 138, k0=min(32mt,80))
//   D2B 3v x (2nt x 2kt)x512 @15360  (cols dn: qlim 74,  k0=nt?16:0)
// Total 21504 shorts.  (Keep in sync with consumer kernel!)
__global__ __launch_bounds__(256) void build_consts(
    const float* __restrict__ fu, const float* __restrict__ fd,
    short* __restrict__ ws)
{
    int idx = blockIdx.x * 256 + threadIdx.x;   // grid covers 21504 exactly
    int l = (idx >> 3) & 63, j = idx & 7;
    int l15 = l & 15, kq = (l >> 4) * 8 + j;
    float val;
    if (idx < 2560) {                         // GtB: B-op, frag = nt
        int nt = idx >> 9;
        int k0 = 8 * nt < 16 ? 8 * nt : 16;
        val = band(k0 + kq, 16 * nt + l15, 74, 43, fu);
    } else if (idx < 7168) {                  // G2A: A-op, frag = mt (0..8)
        int mt = (idx - 2560) >> 9;
        int k0 = 8 * mt < 48 ? 8 * mt : 48;
        val = band(k0 + kq, 16 * mt + l15, 138, 75, fu);
    } else if (idx < 15360) {                 // DA: A-op, frag = (v, mt*2+kt)
        int rel = idx - 7168;
        int v = (rel >> 12) ? 2 : 0;          // by=0 -> v0, by=1 -> v2
        int fi = (rel & 4095) >> 9;
        int mt = fi >> 1, kt = fi & 1;
        int k0 = 32 * mt < 80 ? 32 * mt : 80;
        val = dband(16 * mt + l15, k0 + 32 * kt + kq, v, 138, fd);
    } else {                                  // D2B: B-op, frag = (v, nt*2+kt)
        int rel = idx - 15360;
        int v = rel >> 11, fi = (rel & 2047) >> 9;
        int nt = fi >> 1, kt = fi & 1;
        int k0 = nt ? 16 : 0;
        val = dband(16 * nt + l15, k0 + 32 * kt + kq, v, 74, fd);
    }
    ws[idx] = (short)f2bf(val);
}

#define XPITCH 48    // Xl  [80 r][48 c]    24 words/row (period-4, 2-way: free)
#define BPITCH 88    // B1t [80 qq][88 r]   44 words/row (period-8)
#define UPITCH 152   // Ut  [80 qq][152 pp] 76 words/row (period-8)
#define TPITCH 88    // T   [64 a][88 qq]

// LDS (shorts): B1t @0 (7040) | Ut @7040 (12160) | Xl aliases Ut head
// (dead after S1, Ut written in S2) | T aliases B1t (dead after S2).
// Total 19200 shorts = 38400 B -> 4 blocks/CU, 32 waves/CU.
__global__ __launch_bounds__(512, 8) void upfirdn_mfma(
    const float* __restrict__ xin_all,
    const float* __restrict__ bias,
    const short* __restrict__ cws,
    float* __restrict__ out)
{
    __shared__ __align__(16) short SH[19200];
    short* B1t = SH;            // [80][88]
    short* Ut  = SH + 7040;     // [80][152]
    short* Xl  = SH + 7040;     // [80][48], dead after S1
    short* T   = SH;            // [64][88], written in S3

    const int tid  = threadIdx.x;
    const int lane = tid & 63, w = tid >> 6;          // 8 waves
    const int l15  = lane & 15, q4 = lane >> 4;
    const int bx = blockIdx.x, by = blockIdx.y, bc = blockIdx.z;
    const int i0 = by * 64, j0 = bx * 32;

    const short* GtB = cws;
    const short* G2A = cws + 2560;
    const short* DA  = cws + 7168  + (by ? 4096 : 0);
    const short* D2B = cws + 15360 + ((bx == 0) ? 0 : (bx == 3) ? 2 : 1) * 2048;

    // ---- Phase 0: load X tile (crop +1, +bias), pads zero. 80x24 int items. ----
    {
        const float* xp = xin_all + (size_t)bc * (130 * 130);
        const float bv = bias[bc & 63];
        const bool colInt = (bx == 1) | (bx == 2);
        int* Xli = (int*)Xl;
        for (int idx = tid; idx < 1920; idx += 512) {
            int r = idx / 24, cp = idx - r * 24;
            int gr = i0 - 5 + r;
            float f0 = 0.f, f1 = 0.f;
            if (r < 75 && (unsigned)gr < 128u && cp < 22) {
                const float* rowp = xp + (gr + 1) * 130 + 1;
                int gc0 = j0 - 5 + 2 * cp;
                if (colInt) {
                    f0 = rowp[gc0] + bv;
                    if (cp < 21) f1 = rowp[gc0 + 1] + bv;
                } else {
                    if ((unsigned)gc0 < 128u) f0 = rowp[gc0] + bv;
                    if (cp < 21 && (unsigned)(gc0 + 1) < 128u)
                        f1 = rowp[gc0 + 1] + bv;
                }
            }
            Xli[r * 24 + cp] = pack_bf2(f0, f1);
        }
    }
    __syncthreads();

    // ---- S1: B1 = X * Gt.  25 tiles (mt 0..4 x nt 0..4), round-robin. ----
    for (int t = w; t < 25; t += 8) {
        const int mt = t / 5, nt = t - mt * 5;
        const int k0 = 8 * nt < 16 ? 8 * nt : 16;
        v8s bf = *(const v8s*)&GtB[nt * 512 + lane * 8];
        v8s a  = *(const v8s*)&Xl[(16 * mt + l15) * XPITCH + k0 + q4 * 8];
        v4f acc = {0.f, 0.f, 0.f, 0.f};
        acc = __builtin_amdgcn_mfma_f32_16x16x32_bf16(a, bf, acc, 0, 0, 0);
        // C: col = qq = 16nt+l15, rows r = 16mt + q4*4 + i
        *(int2*)&B1t[(16 * nt + l15) * BPITCH + 16 * mt + q4 * 4] =
            make_int2(pack_bf2(acc[0], acc[1]), pack_bf2(acc[2], acc[3]));
    }
    __syncthreads();

    // ---- S2: U = leaky(G2 * B1).  45 tiles (mt 0..8 x nt 0..4). ----
    for (int t = w; t < 45; t += 8) {
        const int mt = t / 5, nt = t - mt * 5;
        const int k0 = 8 * mt < 48 ? 8 * mt : 48;
        v8s af = *(const v8s*)&G2A[mt * 512 + lane * 8];
        v8s b  = *(const v8s*)&B1t[(16 * nt + l15) * BPITCH + k0 + q4 * 8];
        v4f acc = {0.f, 0.f, 0.f, 0.f};
        acc = __builtin_amdgcn_mfma_f32_16x16x32_bf16(af, b, acc, 0, 0, 0);
#pragma unroll
        for (int i = 0; i < 4; ++i)
            acc[i] = GAIN_C * acc[i] + NEG_C * fminf(acc[i], 0.f);
        // C: col = qq = 16nt+l15, rows pp = 16mt + q4*4 + i
        *(int2*)&Ut[(16 * nt + l15) * UPITCH + 16 * mt + q4 * 4] =
            make_int2(pack_bf2(acc[0], acc[1]), pack_bf2(acc[2], acc[3]));
    }
    __syncthreads();

    // ---- S3: T = D * U.  20 tiles (mt 0..3 x nt 0..4), Kwin64. ----
    for (int t = w; t < 20; t += 8) {
        const int mt = t / 5, nt = t - mt * 5;
        const int k0 = 32 * mt < 80 ? 32 * mt : 80;
        v4f acc = {0.f, 0.f, 0.f, 0.f};
#pragma unroll
        for (int kt = 0; kt < 2; ++kt) {
            v8s a = *(const v8s*)&DA[(mt * 2 + kt) * 512 + lane * 8];
            v8s b = *(const v8s*)&Ut[(16 * nt + l15) * UPITCH
                                     + k0 + 32 * kt + q4 * 8];
            acc = __builtin_amdgcn_mfma_f32_16x16x32_bf16(a, b, acc, 0, 0, 0);
        }
        // C: col = qq = 16nt+l15, rows a = 16mt + q4*4 + i  (b16 scatter)
#pragma unroll
        for (int i = 0; i < 4; ++i)
            T[(16 * mt + q4 * 4 + i) * TPITCH + 16 * nt + l15] =
                (short)f2bf(acc[i]);
    }
    __syncthreads();

    // ---- S4: Out = T * D2t.  8 tiles: wave w -> (mt = w>>1, nt = w&1). ----
    {
        const int mt = w >> 1, nt = w & 1;
        const int k0 = nt ? 16 : 0;
        v4f acc = {0.f, 0.f, 0.f, 0.f};
#pragma unroll
        for (int kt = 0; kt < 2; ++kt) {
            v8s a = *(const v8s*)&T[(16 * mt + l15) * TPITCH + k0 + 32 * kt + q4 * 8];
            v8s b = *(const v8s*)&D2B[(nt * 2 + kt) * 512 + lane * 8];
            acc = __builtin_amdgcn_mfma_f32_16x16x32_bf16(a, b, acc, 0, 0, 0);
        }
        float* op = out + (size_t)bc * 16384
                  + (size_t)(i0 + 16 * mt + q4 * 4) * 128 + (j0 + 16 * nt + l15);
#pragma unroll
        for (int i = 0; i < 4; ++i) op[i * 128] = acc[i];
    }
}

extern "C" void kernel_launch(void* const* d_in, const int* in_sizes, int n_in,
                              void* d_out, int out_size, void* d_ws, size_t ws_size,
                              hipStream_t stream) {
    const float* x  = (const float*)d_in[0];
    const float* bs = (const float*)d_in[1];
    const float* fu = (const float*)d_in[2];
    const float* fd = (const float*)d_in[3];
    float* outp = (float*)d_out;
    short* ws = (short*)d_ws;

    build_consts<<<84, 256, 0, stream>>>(fu, fd, ws);    // 21504 elems
    upfirdn_mfma<<<dim3(4, 2, 512), 512, 0, stream>>>(x, bs, ws, outp);
}

// Round 4
// 118.358 us; speedup vs baseline: 1.1033x; 1.0188x over previous
//
#include <hip/hip_runtime.h>

// Fused UpFIRDn2d via banded MFMA chain: crop(1) -> +bias -> repeat-up x2 ->
// sep 12-tap FIR -> leaky_relu(0.2)*sqrt(2) -> sep 12-tap FIR -> down x2.
// x: (8,64,130,130) f32; out: (8,64,128,128) f32.
//
// Round 10 = Round 9 resubmitted verbatim (round-9 bench died on container
// acquisition, not the kernel; coverage/VGPR audit re-done, no code change).
// Round 9: ILP batching. Round-8 showed VGPR_Count=16 -> zero ILP: runtime
// trip counts blocked unrolling, so every tile was a serialized
// load(200cy) -> ds_read(120cy) -> MFMA -> write chain, and duration was
// invariant (~52us) under occupancy/barrier changes. Fix: compile-time tile
// counts per wave (wave-uniform if between two template instantiations, no
// padded/duplicate tiles), each chunk issues ALL loads, then ALL MFMAs, then
// ALL writes. launch_bounds (512,6): VGPR cap ~85 (peak need ~60), wave cap
// 24/CU (round 8 proved occupancy non-binding at 32).
// Geometry/LDS/tables identical to round 8:
//   S1: B1[r][qq]  = sum_c  X[r][c]   * Gt[c][qq]    M80  N80  Kwin32 (25 tiles)
//   S2: U [pp][qq] = sum_r  G2[pp][r] * B1[r][qq]    M144 N80  Kwin32 (45), leaky
//   S3: T [a][qq]  = sum_pp D[a][pp]  * U[pp][qq]    M64  N80  Kwin64 (20)
//   S4: Out[a][j]  = sum_qq T[a][qq]  * D2t[qq][j]   M64  N32  Kwin64 (8)
// Edge clipping folded into 2 variants of D (by) and 3 of D2t (bx).

#define GAIN_C 1.4142135623730951f
#define NEG_C ((0.2f - 1.0f) * GAIN_C)

typedef short v8s __attribute__((ext_vector_type(8)));
typedef float v4f __attribute__((ext_vector_type(4)));

__device__ __forceinline__ int f2bf(float f) {   // fp32 -> bf16 bits (RNE)
    unsigned u = __float_as_uint(f);
    return (int)((u + 0x7FFFu + ((u >> 16) & 1u)) >> 16) & 0xFFFF;
}
__device__ __forceinline__ int pack_bf2(float a, float b) {
#if __has_builtin(__builtin_amdgcn_cvt_pk_bf16_f32)
    typedef __bf16 bf2 __attribute__((ext_vector_type(2)));
    bf2 r = __builtin_amdgcn_cvt_pk_bf16_f32(a, b);
    int o; __builtin_memcpy(&o, &r, 4); return o;
#else
    return f2bf(a) | (f2bf(b) << 16);
#endif
}

// band(x, q): up-conv weight linking local input index x to local up index q.
// qlim/xlim: valid extents of the local windows (cols: 74/43, rows: 138/75).
__device__ float band(int x, int q, int qlim, int xlim, const float* fu) {
    if (q >= qlim || x >= xlim || x < 0) return 0.f;
    int p = q >> 1, d = x - p;
    if (q & 1) {
        if (d < 0 || d > 6) return 0.f;
        if (d == 0) return fu[0];
        if (d == 6) return fu[11];
        return fu[2 * d - 1] + fu[2 * d];
    } else {
        if (d < 0 || d > 5) return 0.f;
        return fu[2 * d] + fu[2 * d + 1];
    }
}
// dband(o, q, v): down-conv weight, out index o, up index q; variant v:
// 0 = first tile (zero q<5), 2 = last tile (zero q>=qlim-5). qlim = up extent.
__device__ float dband(int o, int q, int v, int qlim, const float* fd) {
    if (q >= qlim || q < 0) return 0.f;
    if (v == 0 && q < 5) return 0.f;
    if (v == 2 && q >= qlim - 5) return 0.f;
    int k = q - 2 * o;
    if (k < 0 || k > 11) return 0.f;
    return fd[k];
}

// ws layout (bf16):
//   GtB 5nt x512            @0       (cols up: qlim 74, xlim 43, k0=min(8nt,16))
//   G2A 9mt x512            @2560    (rows up: qlim 138, xlim 75, k0=min(8mt,48))
//   DA  2v x (4mt x 2kt)x512 @7168   (rows dn: qlim 138, k0=min(32mt,80))
//   D2B 3v x (2nt x 2kt)x512 @15360  (cols dn: qlim 74,  k0=nt?16:0)
// Total 21504 shorts.  (Keep in sync with consumer kernel!)
__global__ __launch_bounds__(256) void build_consts(
    const float* __restrict__ fu, const float* __restrict__ fd,
    short* __restrict__ ws)
{
    int idx = blockIdx.x * 256 + threadIdx.x;   // grid covers 21504 exactly
    int l = (idx >> 3) & 63, j = idx & 7;
    int l15 = l & 15, kq = (l >> 4) * 8 + j;
    float val;
    if (idx < 2560) {                         // GtB: B-op, frag = nt
        int nt = idx >> 9;
        int k0 = 8 * nt < 16 ? 8 * nt : 16;
        val = band(k0 + kq, 16 * nt + l15, 74, 43, fu);
    } else if (idx < 7168) {                  // G2A: A-op, frag = mt (0..8)
        int mt = (idx - 2560) >> 9;
        int k0 = 8 * mt < 48 ? 8 * mt : 48;
        val = band(k0 + kq, 16 * mt + l15, 138, 75, fu);
    } else if (idx < 15360) {                 // DA: A-op, frag = (v, mt*2+kt)
        int rel = idx - 7168;
        int v = (rel >> 12) ? 2 : 0;          // by=0 -> v0, by=1 -> v2
        int fi = (rel & 4095) >> 9;
        int mt = fi >> 1, kt = fi & 1;
        int k0 = 32 * mt < 80 ? 32 * mt : 80;
        val = dband(16 * mt + l15, k0 + 32 * kt + kq, v, 138, fd);
    } else {                                  // D2B: B-op, frag = (v, nt*2+kt)
        int rel = idx - 15360;
        int v = rel >> 11, fi = (rel & 2047) >> 9;
        int nt = fi >> 1, kt = fi & 1;
        int k0 = nt ? 16 : 0;
        val = dband(16 * nt + l15, k0 + 32 * kt + kq, v, 74, fd);
    }
    ws[idx] = (short)f2bf(val);
}

#define XPITCH 48    // Xl  [80 r][48 c]    24 words/row (period-4, 2-way: free)
#define BPITCH 88    // B1t [80 qq][88 r]   44 words/row (period-8)
#define UPITCH 152   // Ut  [80 qq][152 pp] 76 words/row (period-8)
#define TPITCH 88    // T   [64 a][88 qq]

// ---- Batched phase chunks: all loads, then all MFMAs, then all writes. ----
template<int K>
__device__ __forceinline__ void s1_chunk(
    int base, const short* __restrict__ GtB, const short* __restrict__ Xl,
    short* __restrict__ B1t, int lane, int l15, int q4)
{
    v8s a[K], bf[K];
    int dst[K];
#pragma unroll
    for (int i = 0; i < K; ++i) {
        const int t = base + i;
        const int mt = t / 5, nt = t - mt * 5;
        const int k0 = 8 * nt < 16 ? 8 * nt : 16;
        bf[i] = *(const v8s*)&GtB[nt * 512 + lane * 8];
        a[i]  = *(const v8s*)&Xl[(16 * mt + l15) * XPITCH + k0 + q4 * 8];
        dst[i] = (16 * nt + l15) * BPITCH + 16 * mt + q4 * 4;
    }
#pragma unroll
    for (int i = 0; i < K; ++i) {
        v4f acc = {0.f, 0.f, 0.f, 0.f};
        acc = __builtin_amdgcn_mfma_f32_16x16x32_bf16(a[i], bf[i], acc, 0, 0, 0);
        // C: col = qq = 16nt+l15, rows r = 16mt + q4*4 + i
        *(int2*)&B1t[dst[i]] = make_int2(pack_bf2(acc[0], acc[1]),
                                         pack_bf2(acc[2], acc[3]));
    }
}

template<int K>
__device__ __forceinline__ void s2_chunk(
    int base, const short* __restrict__ G2A, const short* __restrict__ B1t,
    short* __restrict__ Ut, int lane, int l15, int q4)
{
    v8s af[K], b[K];
    int dst[K];
#pragma unroll
    for (int i = 0; i < K; ++i) {
        const int t = base + i;
        const int mt = t / 5, nt = t - mt * 5;
        const int k0 = 8 * mt < 48 ? 8 * mt : 48;
        af[i] = *(const v8s*)&G2A[mt * 512 + lane * 8];
        b[i]  = *(const v8s*)&B1t[(16 * nt + l15) * BPITCH + k0 + q4 * 8];
        dst[i] = (16 * nt + l15) * UPITCH + 16 * mt + q4 * 4;
    }
#pragma unroll
    for (int i = 0; i < K; ++i) {
        v4f acc = {0.f, 0.f, 0.f, 0.f};
        acc = __builtin_amdgcn_mfma_f32_16x16x32_bf16(af[i], b[i], acc, 0, 0, 0);
#pragma unroll
        for (int j = 0; j < 4; ++j)
            acc[j] = GAIN_C * acc[j] + NEG_C * fminf(acc[j], 0.f);
        // C: col = qq = 16nt+l15, rows pp = 16mt + q4*4 + i
        *(int2*)&Ut[dst[i]] = make_int2(pack_bf2(acc[0], acc[1]),
                                        pack_bf2(acc[2], acc[3]));
    }
}

template<int K>
__device__ __forceinline__ void s3_chunk(
    int base, const short* __restrict__ DA, const short* __restrict__ Ut,
    short* __restrict__ T, int lane, int l15, int q4)
{
    v8s a0[K], a1[K], b0[K], b1[K];
    int mtA[K], ntA[K];
#pragma unroll
    for (int i = 0; i < K; ++i) {
        const int t = base + i;
        const int mt = t / 5, nt = t - mt * 5;
        const int k0 = 32 * mt < 80 ? 32 * mt : 80;
        mtA[i] = mt; ntA[i] = nt;
        a0[i] = *(const v8s*)&DA[(mt * 2 + 0) * 512 + lane * 8];
        a1[i] = *(const v8s*)&DA[(mt * 2 + 1) * 512 + lane * 8];
        b0[i] = *(const v8s*)&Ut[(16 * nt + l15) * UPITCH + k0 + q4 * 8];
        b1[i] = *(const v8s*)&Ut[(16 * nt + l15) * UPITCH + k0 + 32 + q4 * 8];
    }
#pragma unroll
    for (int i = 0; i < K; ++i) {
        v4f acc = {0.f, 0.f, 0.f, 0.f};
        acc = __builtin_amdgcn_mfma_f32_16x16x32_bf16(a0[i], b0[i], acc, 0, 0, 0);
        acc = __builtin_amdgcn_mfma_f32_16x16x32_bf16(a1[i], b1[i], acc, 0, 0, 0);
        // C: col = qq = 16nt+l15, rows a = 16mt + q4*4 + j  (b16 scatter)
#pragma unroll
        for (int j = 0; j < 4; ++j)
            T[(16 * mtA[i] + q4 * 4 + j) * TPITCH + 16 * ntA[i] + l15] =
                (short)f2bf(acc[j]);
    }
}

// LDS (shorts): B1t @0 (7040) | Ut @7040 (12160) | Xl aliases Ut head
// (dead after S1, Ut written in S2) | T aliases B1t (dead after S2).
// Total 19200 shorts = 38400 B.
__global__ __launch_bounds__(512, 6) void upfirdn_mfma(
    const float* __restrict__ xin_all,
    const float* __restrict__ bias,
    const short* __restrict__ cws,
    float* __restrict__ out)
{
    __shared__ __align__(16) short SH[19200];
    short* B1t = SH;            // [80][88]
    short* Ut  = SH + 7040;     // [80][152]
    short* Xl  = SH + 7040;     // [80][48], dead after S1
    short* T   = SH;            // [64][88], written in S3

    const int tid  = threadIdx.x;
    const int lane = tid & 63, w = tid >> 6;          // 8 waves
    const int l15  = lane & 15, q4 = lane >> 4;
    const int bx = blockIdx.x, by = blockIdx.y, bc = blockIdx.z;
    const int i0 = by * 64, j0 = bx * 32;

    const short* GtB = cws;
    const short* G2A = cws + 2560;
    const short* DA  = cws + 7168  + (by ? 4096 : 0);
    const short* D2B = cws + 15360 + ((bx == 0) ? 0 : (bx == 3) ? 2 : 1) * 2048;

    // ---- Phase 0: load X tile (crop +1, +bias), pads zero. 80x24 int items. ----
    {
        const float* xp = xin_all + (size_t)bc * (130 * 130);
        const float bv = bias[bc & 63];
        const bool colInt = (bx == 1) | (bx == 2);
        int* Xli = (int*)Xl;
        for (int idx = tid; idx < 1920; idx += 512) {
            int r = idx / 24, cp = idx - r * 24;
            int gr = i0 - 5 + r;
            float f0 = 0.f, f1 = 0.f;
            if (r < 75 && (unsigned)gr < 128u && cp < 22) {
                const float* rowp = xp + (gr + 1) * 130 + 1;
                int gc0 = j0 - 5 + 2 * cp;
                if (colInt) {
                    f0 = rowp[gc0] + bv;
                    if (cp < 21) f1 = rowp[gc0 + 1] + bv;
                } else {
                    if ((unsigned)gc0 < 128u) f0 = rowp[gc0] + bv;
                    if (cp < 21 && (unsigned)(gc0 + 1) < 128u)
                        f1 = rowp[gc0 + 1] + bv;
                }
            }
            Xli[r * 24 + cp] = pack_bf2(f0, f1);
        }
    }
    __syncthreads();

    // ---- S1: 25 tiles. wave 0: t 0..3; wave w>0: t 3w+1 .. 3w+3. ----
    if (w == 0) s1_chunk<4>(0,         GtB, Xl, B1t, lane, l15, q4);
    else        s1_chunk<3>(3 * w + 1, GtB, Xl, B1t, lane, l15, q4);
    __syncthreads();

    // ---- S2: 45 tiles. waves 0..4: 6 tiles @6w; waves 5..7: 5 @5w+5. ----
    if (w < 5) s2_chunk<6>(6 * w,     G2A, B1t, Ut, lane, l15, q4);
    else       s2_chunk<5>(5 * w + 5, G2A, B1t, Ut, lane, l15, q4);
    __syncthreads();

    // ---- S3: 20 tiles. waves 0..3: 3 tiles @3w; waves 4..7: 2 @2w+4. ----
    if (w < 4) s3_chunk<3>(3 * w,     DA, Ut, T, lane, l15, q4);
    else       s3_chunk<2>(2 * w + 4, DA, Ut, T, lane, l15, q4);
    __syncthreads();

    // ---- S4: Out = T * D2t.  8 tiles: wave w -> (mt = w>>1, nt = w&1). ----
    {
        const int mt = w >> 1, nt = w & 1;
        const int k0 = nt ? 16 : 0;
        v8s a0 = *(const v8s*)&T[(16 * mt + l15) * TPITCH + k0 + q4 * 8];
        v8s a1 = *(const v8s*)&T[(16 * mt + l15) * TPITCH + k0 + 32 + q4 * 8];
        v8s b0 = *(const v8s*)&D2B[(nt * 2 + 0) * 512 + lane * 8];
        v8s b1 = *(const v8s*)&D2B[(nt * 2 + 1) * 512 + lane * 8];
        v4f acc = {0.f, 0.f, 0.f, 0.f};
        acc = __builtin_amdgcn_mfma_f32_16x16x32_bf16(a0, b0, acc, 0, 0, 0);
        acc = __builtin_amdgcn_mfma_f32_16x16x32_bf16(a1, b1, acc, 0, 0, 0);
        float* op = out + (size_t)bc * 16384
                  + (size_t)(i0 + 16 * mt + q4 * 4) * 128 + (j0 + 16 * nt + l15);
#pragma unroll
        for (int i = 0; i < 4; ++i) op[i * 128] = acc[i];
    }
}

extern "C" void kernel_launch(void* const* d_in, const int* in_sizes, int n_in,
                              void* d_out, int out_size, void* d_ws, size_t ws_size,
                              hipStream_t stream) {
    const float* x  = (const float*)d_in[0];
    const float* bs = (const float*)d_in[1];
    const float* fu = (const float*)d_in[2];
    const float* fd = (const float*)d_in[3];
    float* outp = (float*)d_out;
    short* ws = (short*)d_ws;

    build_consts<<<84, 256, 0, stream>>>(fu, fd, ws);    // 21504 elems
    upfirdn_mfma<<<dim3(4, 2, 512), 512, 0, stream>>>(x, bs, ws, outp);
}